// Round 1
// baseline (582.901 us; speedup 1.0000x reference)
//
#include <hip/hip_runtime.h>

// Problem constants (B=4,H=16,N=8192,D=E=64, fp32 in/out)
constexpr int BH   = 64;      // B*H
constexpr int NN   = 8192;
constexpr int DD   = 64;
constexpr int EE   = 64;
constexpr int ST   = 72;      // LDS stride in bf16 elems: 144 B, 16B-aligned, breaks pow2 banks
constexpr int NSPLIT = 32;    // blocks per (b,h)
constexpr int ROWS = NN / NSPLIT;   // 256 rows per block
constexpr int CHUNK = 64;           // rows per inner iteration
constexpr float EPS_ = 1e-10f;

typedef __attribute__((ext_vector_type(8))) short short8;   // 8 bf16 = 4 VGPRs (A/B frag)
typedef __attribute__((ext_vector_type(4))) float f32x4;    // C/D frag

#define MFMA16(a, b, c) __builtin_amdgcn_mfma_f32_16x16x32_bf16((a), (b), (c), 0, 0, 0)

__device__ __forceinline__ unsigned short f2bf(float f) {
  union { float f; unsigned u; } v; v.f = f;
  unsigned r = v.u + 0x7fffu + ((v.u >> 16) & 1u);   // round-to-nearest-even
  return (unsigned short)(r >> 16);
}
__device__ __forceinline__ float bf2f(unsigned short s) {
  union { unsigned u; float f; } v; v.u = ((unsigned)s) << 16;
  return v.f;
}
__device__ __forceinline__ float elu1(float x) {     // elu(x)+1
  return x > 0.0f ? x + 1.0f : __expf(x);
}

// ---------------------------------------------------------------------------
// Kernel 0: initialize new_kv/new_norm output regions with past values
// (d_out is re-poisoned before every launch; k-side kernel atomically adds)
// ---------------------------------------------------------------------------
__global__ void fw_init_kernel(const float* __restrict__ past_kv,
                               const float* __restrict__ past_norm,
                               float* __restrict__ out_kv,
                               float* __restrict__ out_norm) {
  int i = blockIdx.x * 256 + threadIdx.x;
  if (i < BH * DD * EE) out_kv[i] = past_kv[i];
  if (i < BH * DD)      out_norm[i] = past_norm[i];
}

// ---------------------------------------------------------------------------
// Kernel A (k-side): k=elu(keys)+1; delta_v = (k@pkv)/(k·pnorm);
// new_kv += k^T (values - delta_v); new_norm += sum_n k
// ---------------------------------------------------------------------------
__global__ __launch_bounds__(256, 3) void fw_kv_kernel(
    const float* __restrict__ keys, const float* __restrict__ values,
    const float* __restrict__ past_kv, const float* __restrict__ past_norm,
    float* __restrict__ out_kv, float* __restrict__ out_norm) {
  __shared__ unsigned short pkvT[EE * ST];   // past_kv^T bf16: [e][d]  (GEMM1 A)
  __shared__ unsigned short kls [CHUNK * ST];// k bf16:       [n][d]  (GEMM1 B)
  __shared__ unsigned short kT  [DD * ST];   // k^T bf16:     [d][n]  (GEMM2 B)
  __shared__ unsigned short vls [CHUNK * ST];// values bf16:  [n][e]
  __shared__ unsigned short vT  [EE * ST];   // v^T bf16:     [e][n]  (GEMM2 A)
  __shared__ float pnorm_s[DD];
  __shared__ float denom_s[CHUNK];
  __shared__ float norm_part[DD];

  const int t  = threadIdx.x;
  const int bh = blockIdx.x & (BH - 1);
  const int split = blockIdx.x >> 6;
  const int row0 = split * ROWS;
  const long kvbase = (long)bh * NN * DD;

  if (t < DD) { pnorm_s[t] = past_norm[bh * DD + t]; norm_part[t] = 0.0f; }
  // stage past_kv -> pkvT (bf16, transposed). Once per block, cost amortized.
  for (int p = 0; p < 4; ++p) {
    int idx = p * 1024 + t * 4;
    int d = idx >> 6, e0 = idx & 63;
    float4 v4 = *(const float4*)&past_kv[(long)bh * DD * EE + idx];
    pkvT[(e0 + 0) * ST + d] = f2bf(v4.x);
    pkvT[(e0 + 1) * ST + d] = f2bf(v4.y);
    pkvT[(e0 + 2) * ST + d] = f2bf(v4.z);
    pkvT[(e0 + 3) * ST + d] = f2bf(v4.w);
  }
  __syncthreads();

  const int l = t & 63, w = t >> 6;     // wave id 0..3
  const int l16 = l & 15, q = l >> 4;   // MFMA lane decomposition

  float na0 = 0.f, na1 = 0.f, na2 = 0.f, na3 = 0.f;  // norm partials (d fixed per thread)
  f32x4 acc2[4];                                      // new_kv^T tiles: e-tile w, d-tiles 0..3
  #pragma unroll
  for (int i = 0; i < 4; ++i) acc2[i] = (f32x4){0.f, 0.f, 0.f, 0.f};

  for (int c = 0; c < ROWS / CHUNK; ++c) {
    const int rowc = row0 + c * CHUNK;

    // ---- phase 1: stage k (both layouts), values, denom ----
    for (int p = 0; p < 4; ++p) {
      int idx = p * 1024 + t * 4;
      int nl = idx >> 6;        // chunk-local row; 16 consecutive threads share nl
      int d0 = idx & 63;        // = (t&15)*4, constant per thread
      float4 k4 = *(const float4*)&keys[kvbase + (long)(rowc + nl) * DD + d0];
      float k0 = elu1(k4.x), k1 = elu1(k4.y), k2 = elu1(k4.z), k3 = elu1(k4.w);
      ushort4 kb; kb.x = f2bf(k0); kb.y = f2bf(k1); kb.z = f2bf(k2); kb.w = f2bf(k3);
      *(ushort4*)&kls[nl * ST + d0] = kb;
      kT[(d0 + 0) * ST + nl] = kb.x;
      kT[(d0 + 1) * ST + nl] = kb.y;
      kT[(d0 + 2) * ST + nl] = kb.z;
      kT[(d0 + 3) * ST + nl] = kb.w;
      float part = k0 * pnorm_s[d0] + k1 * pnorm_s[d0 + 1]
                 + k2 * pnorm_s[d0 + 2] + k3 * pnorm_s[d0 + 3];
      part += __shfl_xor(part, 1);
      part += __shfl_xor(part, 2);
      part += __shfl_xor(part, 4);
      part += __shfl_xor(part, 8);
      if (l16 == 0) denom_s[nl] = part;
      na0 += k0; na1 += k1; na2 += k2; na3 += k3;
      float4 v4 = *(const float4*)&values[kvbase + (long)(rowc + nl) * DD + d0];
      ushort4 vb; vb.x = f2bf(v4.x); vb.y = f2bf(v4.y); vb.z = f2bf(v4.z); vb.w = f2bf(v4.w);
      *(ushort4*)&vls[nl * ST + d0] = vb;
    }
    __syncthreads();

    // ---- GEMM1 (transposed): D[e][n] = sum_d pkvT[e][d]*k[n][d]; wave w -> rows nb..nb+15
    const int nb = w * 16;
    f32x4 acc1[4];
    #pragma unroll
    for (int i = 0; i < 4; ++i) acc1[i] = (f32x4){0.f, 0.f, 0.f, 0.f};
    #pragma unroll
    for (int s = 0; s < 2; ++s) {
      short8 bfrag = *(const short8*)&kls[(nb + l16) * ST + s * 32 + q * 8];
      #pragma unroll
      for (int et = 0; et < 4; ++et) {
        short8 afrag = *(const short8*)&pkvT[(et * 16 + l16) * ST + s * 32 + q * 8];
        acc1[et] = MFMA16(afrag, bfrag, acc1[et]);
      }
    }
    // v = values - numer/denom, write v^T (bf16) for GEMM2 A-operand
    const float rd = 1.0f / fmaxf(denom_s[nb + l16], EPS_);
    #pragma unroll
    for (int et = 0; et < 4; ++et) {
      #pragma unroll
      for (int i = 0; i < 4; ++i) {
        int e = et * 16 + q * 4 + i;     // C-layout: row=e, col=n=nb+l16
        float val = bf2f(vls[(nb + l16) * ST + e]);
        float v = val - acc1[et][i] * rd;
        vT[e * ST + nb + l16] = f2bf(v);
      }
    }
    __syncthreads();

    // ---- GEMM2: new_kv^T[e][d] += sum_n vT[e][n]*kT[d][n]; wave w = e-tile w
    #pragma unroll
    for (int s = 0; s < 2; ++s) {
      short8 afrag = *(const short8*)&vT[(w * 16 + l16) * ST + s * 32 + q * 8];
      #pragma unroll
      for (int dt = 0; dt < 4; ++dt) {
        short8 bfrag = *(const short8*)&kT[(dt * 16 + l16) * ST + s * 32 + q * 8];
        acc2[dt] = MFMA16(afrag, bfrag, acc2[dt]);
      }
    }
    __syncthreads();   // protect kls/kT/vls/vT before next chunk's phase 1
  }

  // ---- epilogue: norm reduce + atomic adds ----
  {
    const int d0 = (t & 15) * 4;
    atomicAdd(&norm_part[d0 + 0], na0);
    atomicAdd(&norm_part[d0 + 1], na1);
    atomicAdd(&norm_part[d0 + 2], na2);
    atomicAdd(&norm_part[d0 + 3], na3);
  }
  __syncthreads();
  if (t < DD) atomicAdd(&out_norm[bh * DD + t], norm_part[t]);
  #pragma unroll
  for (int dt = 0; dt < 4; ++dt) {
    #pragma unroll
    for (int i = 0; i < 4; ++i) {
      int d = dt * 16 + l16;
      int e = w * 16 + q * 4 + i;
      atomicAdd(&out_kv[(long)bh * DD * EE + d * EE + e], acc2[dt][i]);
    }
  }
}

// ---------------------------------------------------------------------------
// Kernel B (q-side): q=elu(queries)+1; mem = (q@pkv)/(q·pnorm);
// out_g = out*g + mem*(1-g)
// ---------------------------------------------------------------------------
__global__ __launch_bounds__(256, 4) void fw_out_kernel(
    const float* __restrict__ queries, const float* __restrict__ outin,
    const float* __restrict__ past_kv, const float* __restrict__ past_norm,
    const float* __restrict__ head_gates, float* __restrict__ out_g) {
  __shared__ unsigned short pkvT[EE * ST];
  __shared__ unsigned short qls [CHUNK * ST];   // q bf16 [n][d]
  __shared__ unsigned short mem_s[CHUNK * ST];  // mem bf16 [n][e]
  __shared__ float pnorm_s[DD];
  __shared__ float denom_s[CHUNK];

  const int t  = threadIdx.x;
  const int bh = blockIdx.x & (BH - 1);
  const int split = blockIdx.x >> 6;
  const int row0 = split * ROWS;
  const long qbase = (long)bh * NN * DD;

  const float hg = head_gates[bh & 15];        // bh = b*H + h -> h = bh%16
  const float g = 1.0f / (1.0f + __expf(-hg));
  const float gm1 = 1.0f - g;

  if (t < DD) pnorm_s[t] = past_norm[bh * DD + t];
  for (int p = 0; p < 4; ++p) {
    int idx = p * 1024 + t * 4;
    int d = idx >> 6, e0 = idx & 63;
    float4 v4 = *(const float4*)&past_kv[(long)bh * DD * EE + idx];
    pkvT[(e0 + 0) * ST + d] = f2bf(v4.x);
    pkvT[(e0 + 1) * ST + d] = f2bf(v4.y);
    pkvT[(e0 + 2) * ST + d] = f2bf(v4.z);
    pkvT[(e0 + 3) * ST + d] = f2bf(v4.w);
  }
  __syncthreads();

  const int l = t & 63, w = t >> 6;
  const int l16 = l & 15, q = l >> 4;

  for (int c = 0; c < ROWS / CHUNK; ++c) {
    const int rowc = row0 + c * CHUNK;

    // phase 1: stage q bf16 + denom
    for (int p = 0; p < 4; ++p) {
      int idx = p * 1024 + t * 4;
      int nl = idx >> 6, d0 = idx & 63;
      float4 q4 = *(const float4*)&queries[qbase + (long)(rowc + nl) * DD + d0];
      float q0 = elu1(q4.x), q1 = elu1(q4.y), q2 = elu1(q4.z), q3 = elu1(q4.w);
      ushort4 qb; qb.x = f2bf(q0); qb.y = f2bf(q1); qb.z = f2bf(q2); qb.w = f2bf(q3);
      *(ushort4*)&qls[nl * ST + d0] = qb;
      float part = q0 * pnorm_s[d0] + q1 * pnorm_s[d0 + 1]
                 + q2 * pnorm_s[d0 + 2] + q3 * pnorm_s[d0 + 3];
      part += __shfl_xor(part, 1);
      part += __shfl_xor(part, 2);
      part += __shfl_xor(part, 4);
      part += __shfl_xor(part, 8);
      if (l16 == 0) denom_s[nl] = part;
    }
    __syncthreads();

    // GEMM (transposed): D[e][n] = sum_d pkvT[e][d]*q[n][d]
    const int nb = w * 16;
    f32x4 acc[4];
    #pragma unroll
    for (int i = 0; i < 4; ++i) acc[i] = (f32x4){0.f, 0.f, 0.f, 0.f};
    #pragma unroll
    for (int s = 0; s < 2; ++s) {
      short8 bfrag = *(const short8*)&qls[(nb + l16) * ST + s * 32 + q * 8];
      #pragma unroll
      for (int et = 0; et < 4; ++et) {
        short8 afrag = *(const short8*)&pkvT[(et * 16 + l16) * ST + s * 32 + q * 8];
        acc[et] = MFMA16(afrag, bfrag, acc[et]);
      }
    }
    const float rd = 1.0f / fmaxf(denom_s[nb + l16], EPS_);
    #pragma unroll
    for (int et = 0; et < 4; ++et) {
      #pragma unroll
      for (int i = 0; i < 4; ++i) {
        int e = et * 16 + q * 4 + i;
        mem_s[(nb + l16) * ST + e] = f2bf(acc[et][i] * rd);
      }
    }
    __syncthreads();

    // final: coalesced blend with `out` and store (mem term scaled by 1-g ~ 4.5e-5)
    for (int p = 0; p < 4; ++p) {
      int idx = p * 1024 + t * 4;
      int nl = idx >> 6, e0 = idx & 63;
      ushort4 mb = *(const ushort4*)&mem_s[nl * ST + e0];
      long goff = qbase + (long)(rowc + nl) * EE + e0;
      float4 o4 = *(const float4*)&outin[goff];
      float4 r;
      r.x = o4.x * g + bf2f(mb.x) * gm1;
      r.y = o4.y * g + bf2f(mb.y) * gm1;
      r.z = o4.z * g + bf2f(mb.z) * gm1;
      r.w = o4.w * g + bf2f(mb.w) * gm1;
      *(float4*)&out_g[goff] = r;
    }
    // no extra sync needed: mem_s next written only after the post-phase1 sync
  }
}

extern "C" void kernel_launch(void* const* d_in, const int* in_sizes, int n_in,
                              void* d_out, int out_size, void* d_ws, size_t ws_size,
                              hipStream_t stream) {
  const float* keys      = (const float*)d_in[0];
  const float* values    = (const float*)d_in[1];
  const float* queries   = (const float*)d_in[2];
  const float* outin     = (const float*)d_in[3];
  const float* past_kv   = (const float*)d_in[4];
  const float* past_norm = (const float*)d_in[5];
  const float* head_gates= (const float*)d_in[6];

  float* out_g    = (float*)d_out;                       // [4,16,8192,64]
  float* out_kv   = out_g + (long)BH * NN * EE;          // [4,16,64,64]
  float* out_norm = out_kv + (long)BH * DD * EE;         // [4,16,64]

  fw_init_kernel<<<(BH * DD * EE + 255) / 256, 256, 0, stream>>>(
      past_kv, past_norm, out_kv, out_norm);
  fw_kv_kernel<<<BH * NSPLIT, 256, 0, stream>>>(
      keys, values, past_kv, past_norm, out_kv, out_norm);
  fw_out_kernel<<<BH * NSPLIT, 256, 0, stream>>>(
      queries, outin, past_kv, past_norm, head_gates, out_g);
}